// Round 7
// baseline (235.084 us; speedup 1.0000x reference)
//
#include <hip/hip_runtime.h>
#include <hip/hip_fp16.h>
#include <math.h>

#define N_NODES 100000
#define N_EDGES 1600000
#define DIM 64
#define CPAD 16      // counters padded to one per 64B cache line

#define SCAN_BS   256
#define SCAN_EPB  1024
#define SCAN_NBLK ((N_NODES + SCAN_EPB - 1) / SCAN_EPB)   // 98

// sigmoid(s*w+b) = rcp(1 + exp2(s*(-w*log2e) + (-b*log2e)))
__device__ __forceinline__ float fast_gate(float s, float wl, float bl2) {
    return __builtin_amdgcn_rcpf(1.0f + __builtin_amdgcn_exp2f(fmaf(s, wl, bl2)));
}

// ---------------------------------------------------------------------------
// 0) x (fp32, 25.6 MB) -> xh (fp16, 12.8 MB): halves gather line traffic.
// ---------------------------------------------------------------------------
__global__ __launch_bounds__(256) void convert_kernel(
    const float* __restrict__ x, ushort* __restrict__ xh)
{
    int t = blockIdx.x * 256 + threadIdx.x;        // 8 floats per thread
    if (t >= N_NODES * DIM / 8) return;
    float4 a = ((const float4*)x)[t * 2];
    float4 b = ((const float4*)x)[t * 2 + 1];
    __half2 h0 = __floats2half2_rn(a.x, a.y);
    __half2 h1 = __floats2half2_rn(a.z, a.w);
    __half2 h2 = __floats2half2_rn(b.x, b.y);
    __half2 h3 = __floats2half2_rn(b.z, b.w);
    uint4 u;
    u.x = *(unsigned*)&h0; u.y = *(unsigned*)&h1;
    u.z = *(unsigned*)&h2; u.w = *(unsigned*)&h3;
    ((uint4*)xh)[t] = u;
}

// ---------------------------------------------------------------------------
// 1) Fused histogram + rank (4 edges/thread, int4 I/O).
// ---------------------------------------------------------------------------
__global__ __launch_bounds__(256) void rank_kernel(
    const int* __restrict__ edge, int* __restrict__ cntp,
    int* __restrict__ rank)
{
    int t = blockIdx.x * 256 + threadIdx.x;
    if (t >= N_EDGES / 4) return;
    int4 r4 = ((const int4*)edge)[t];
    int4 o;
    o.x = atomicAdd(&cntp[(size_t)r4.x * CPAD], 1);
    o.y = atomicAdd(&cntp[(size_t)r4.y * CPAD], 1);
    o.z = atomicAdd(&cntp[(size_t)r4.z * CPAD], 1);
    o.w = atomicAdd(&cntp[(size_t)r4.w * CPAD], 1);
    ((int4*)rank)[t] = o;
}

// ---------------------------------------------------------------------------
// 2a) Per-block reduce of padded cnt.
// ---------------------------------------------------------------------------
__global__ __launch_bounds__(SCAN_BS) void scan_reduce_kernel(
    const int* __restrict__ cntp, int* __restrict__ bsum)
{
    __shared__ int ls[SCAN_BS];
    int base = blockIdx.x * SCAN_EPB;
    int s = 0;
    #pragma unroll
    for (int i = 0; i < 4; ++i) {
        int idx = base + threadIdx.x + i * SCAN_BS;
        s += (idx < N_NODES) ? cntp[(size_t)idx * CPAD] : 0;
    }
    ls[threadIdx.x] = s;
    __syncthreads();
    for (int o = SCAN_BS / 2; o > 0; o >>= 1) {
        if (threadIdx.x < o) ls[threadIdx.x] += ls[threadIdx.x + o];
        __syncthreads();
    }
    if (threadIdx.x == 0) bsum[blockIdx.x] = ls[0];
}

// ---------------------------------------------------------------------------
// 2b) Exclusive scan of the 98 block sums.
// ---------------------------------------------------------------------------
__global__ __launch_bounds__(128) void scan_top_kernel(int* __restrict__ bsum)
{
    __shared__ int ls[SCAN_NBLK];
    if (threadIdx.x < SCAN_NBLK) ls[threadIdx.x] = bsum[threadIdx.x];
    __syncthreads();
    if (threadIdx.x == 0) {
        int run = 0;
        for (int i = 0; i < SCAN_NBLK; ++i) { int t = ls[i]; ls[i] = run; run += t; }
    }
    __syncthreads();
    if (threadIdx.x < SCAN_NBLK) bsum[threadIdx.x] = ls[threadIdx.x];
}

// ---------------------------------------------------------------------------
// 2c) Per-block rescan -> off[] (exclusive prefix; off[N] = E).
// ---------------------------------------------------------------------------
__global__ __launch_bounds__(SCAN_BS) void scan_down_kernel(
    const int* __restrict__ cntp, const int* __restrict__ bsum,
    int* __restrict__ off)
{
    __shared__ int ls[SCAN_BS];
    const int tid  = threadIdx.x;
    const int base = blockIdx.x * SCAN_EPB;

    if (blockIdx.x == 0 && tid == 0) off[N_NODES] = N_EDGES;

    int v[4]; int tsum = 0;
    #pragma unroll
    for (int i = 0; i < 4; ++i) {
        int idx = base + tid * 4 + i;
        v[i] = (idx < N_NODES) ? cntp[(size_t)idx * CPAD] : 0;
        tsum += v[i];
    }
    ls[tid] = tsum;
    __syncthreads();
    for (int o = 1; o < SCAN_BS; o <<= 1) {
        int t = (tid >= o) ? ls[tid - o] : 0;
        __syncthreads();
        ls[tid] += t;
        __syncthreads();
    }
    int run = bsum[blockIdx.x] + ls[tid] - tsum;
    #pragma unroll
    for (int i = 0; i < 4; ++i) {
        int idx = base + tid * 4 + i;
        if (idx < N_NODES) off[idx] = run;
        run += v[i];
    }
}

// ---------------------------------------------------------------------------
// 3) Atomic-free scatter (4 edges/thread): slot = off[row] + rank[e].
// ---------------------------------------------------------------------------
__global__ __launch_bounds__(256) void scatter_kernel(
    const int* __restrict__ edge, const int* __restrict__ rank,
    const int* __restrict__ off,  int* __restrict__ scol)
{
    int t = blockIdx.x * 256 + threadIdx.x;
    if (t >= N_EDGES / 4) return;
    int4 r4 = ((const int4*)edge)[t];
    int4 c4 = ((const int4*)(edge + N_EDGES))[t];
    int4 k4 = ((const int4*)rank)[t];
    scol[off[r4.x] + k4.x] = c4.x;
    scol[off[r4.y] + k4.y] = c4.y;
    scol[off[r4.z] + k4.z] = c4.z;
    scol[off[r4.w] + k4.w] = c4.w;
}

// ---------------------------------------------------------------------------
// 4) Fused gather+gate+mean+Linear+GELU over fp16 x.
//    1 node/wave, 4 waves/block (25000 blocks).
//    lane l: edge group eg = l>>3 (8 groups), feature oct fg = (l&7)*8.
//    One uint4 load = 8 halves; 8 groups cover 8 edges per instruction.
//    Phase A: lane=edge -> {col, |curv diff|} into LDS once per edge.
//    Reduce via shfl_xor(8|16|32); Linear via float4 LDS reads.
// ---------------------------------------------------------------------------
__global__ __launch_bounds__(256) void node_kernel(
    const ushort* __restrict__ xh,  const float* __restrict__ curv,
    const int*   __restrict__ off,  const int* __restrict__ scol,
    const float* __restrict__ Wc,   const float* __restrict__ bc,
    const float* __restrict__ Wl,   const float* __restrict__ bl,
    float* __restrict__ out)
{
    __shared__ float Ws[64][65];
    __shared__ float msl[4][64];
    __shared__ int2  ecd[4][64];

    const int tid = threadIdx.x;
    #pragma unroll
    for (int i = tid; i < DIM * DIM; i += 256)
        Ws[i >> 6][i & 63] = Wl[i];
    __syncthreads();

    const int sub  = tid >> 6;          // wave in block
    const int lane = tid & 63;
    const int eg   = lane >> 3;         // edge group 0..7
    const int fg   = (lane & 7) << 3;   // feature oct base
    const int d    = lane;              // output feature for Linear
    const int node = blockIdx.x * 4 + sub;   // grid exact

    const float L2E = 1.44269504088896340736f;
    float wl[8], bq[8];
    {
        const float4 w0 = *(const float4*)&Wc[fg];
        const float4 w1 = *(const float4*)&Wc[fg + 4];
        const float4 b0 = *(const float4*)&bc[fg];
        const float4 b1 = *(const float4*)&bc[fg + 4];
        wl[0] = -w0.x * L2E; wl[1] = -w0.y * L2E; wl[2] = -w0.z * L2E; wl[3] = -w0.w * L2E;
        wl[4] = -w1.x * L2E; wl[5] = -w1.y * L2E; wl[6] = -w1.z * L2E; wl[7] = -w1.w * L2E;
        bq[0] = -b0.x * L2E; bq[1] = -b0.y * L2E; bq[2] = -b0.z * L2E; bq[3] = -b0.w * L2E;
        bq[4] = -b1.x * L2E; bq[5] = -b1.y * L2E; bq[6] = -b1.z * L2E; bq[7] = -b1.w * L2E;
    }
    const float bld = bl[d];

    const int   start = off[node];
    const int   deg   = off[node + 1] - start;
    const float cn    = curv[node];

    float a[8];
    #pragma unroll
    for (int j = 0; j < 8; ++j) a[j] = 0.0f;

    for (int kb = 0; kb < deg; kb += 64) {
        const int pn = min(64, deg - kb);
        // Phase A: one lane per edge
        if (lane < pn) {
            int   c  = scol[start + kb + lane];
            float cd = fabsf(cn - curv[c]);
            ecd[sub][lane] = make_int2(c, __float_as_int(cd));
        }
        // Phase B: group eg handles edges k = eg, eg+8, ...
        int k = eg;
        for (; k + 8 < pn; k += 16) {               // 2 edges per lane per iter
            int2 p0 = ecd[sub][k];
            int2 p1 = ecd[sub][k + 8];
            float s0 = __int_as_float(p0.y);
            float s1 = __int_as_float(p1.y);
            uint4 v0 = *(const uint4*)&xh[((unsigned)p0.x << 6) + fg];
            uint4 v1 = *(const uint4*)&xh[((unsigned)p1.x << 6) + fg];
            float2 f0 = __half22float2(*(__half2*)&v0.x);
            float2 f1 = __half22float2(*(__half2*)&v0.y);
            float2 f2 = __half22float2(*(__half2*)&v0.z);
            float2 f3 = __half22float2(*(__half2*)&v0.w);
            a[0] = fmaf(f0.x, fast_gate(s0, wl[0], bq[0]), a[0]);
            a[1] = fmaf(f0.y, fast_gate(s0, wl[1], bq[1]), a[1]);
            a[2] = fmaf(f1.x, fast_gate(s0, wl[2], bq[2]), a[2]);
            a[3] = fmaf(f1.y, fast_gate(s0, wl[3], bq[3]), a[3]);
            a[4] = fmaf(f2.x, fast_gate(s0, wl[4], bq[4]), a[4]);
            a[5] = fmaf(f2.y, fast_gate(s0, wl[5], bq[5]), a[5]);
            a[6] = fmaf(f3.x, fast_gate(s0, wl[6], bq[6]), a[6]);
            a[7] = fmaf(f3.y, fast_gate(s0, wl[7], bq[7]), a[7]);
            float2 g0 = __half22float2(*(__half2*)&v1.x);
            float2 g1 = __half22float2(*(__half2*)&v1.y);
            float2 g2 = __half22float2(*(__half2*)&v1.z);
            float2 g3 = __half22float2(*(__half2*)&v1.w);
            a[0] = fmaf(g0.x, fast_gate(s1, wl[0], bq[0]), a[0]);
            a[1] = fmaf(g0.y, fast_gate(s1, wl[1], bq[1]), a[1]);
            a[2] = fmaf(g1.x, fast_gate(s1, wl[2], bq[2]), a[2]);
            a[3] = fmaf(g1.y, fast_gate(s1, wl[3], bq[3]), a[3]);
            a[4] = fmaf(g2.x, fast_gate(s1, wl[4], bq[4]), a[4]);
            a[5] = fmaf(g2.y, fast_gate(s1, wl[5], bq[5]), a[5]);
            a[6] = fmaf(g3.x, fast_gate(s1, wl[6], bq[6]), a[6]);
            a[7] = fmaf(g3.y, fast_gate(s1, wl[7], bq[7]), a[7]);
        }
        if (k < pn) {
            int2 p0 = ecd[sub][k];
            float s0 = __int_as_float(p0.y);
            uint4 v0 = *(const uint4*)&xh[((unsigned)p0.x << 6) + fg];
            float2 f0 = __half22float2(*(__half2*)&v0.x);
            float2 f1 = __half22float2(*(__half2*)&v0.y);
            float2 f2 = __half22float2(*(__half2*)&v0.z);
            float2 f3 = __half22float2(*(__half2*)&v0.w);
            a[0] = fmaf(f0.x, fast_gate(s0, wl[0], bq[0]), a[0]);
            a[1] = fmaf(f0.y, fast_gate(s0, wl[1], bq[1]), a[1]);
            a[2] = fmaf(f1.x, fast_gate(s0, wl[2], bq[2]), a[2]);
            a[3] = fmaf(f1.y, fast_gate(s0, wl[3], bq[3]), a[3]);
            a[4] = fmaf(f2.x, fast_gate(s0, wl[4], bq[4]), a[4]);
            a[5] = fmaf(f2.y, fast_gate(s0, wl[5], bq[5]), a[5]);
            a[6] = fmaf(f3.x, fast_gate(s0, wl[6], bq[6]), a[6]);
            a[7] = fmaf(f3.y, fast_gate(s0, wl[7], bq[7]), a[7]);
        }
    }

    // sum the 8 edge groups (lanes l, l^8, l^16, ..., l^56)
    #pragma unroll
    for (int j = 0; j < 8; ++j) {
        a[j] += __shfl_xor(a[j], 8);
        a[j] += __shfl_xor(a[j], 16);
        a[j] += __shfl_xor(a[j], 32);
    }

    const float inv = __builtin_amdgcn_rcpf(fmaxf((float)deg, 1.0f));
    if (eg == 0) {
        *(float4*)&msl[sub][lane * 8]     = make_float4(a[0]*inv, a[1]*inv, a[2]*inv, a[3]*inv);
        *(float4*)&msl[sub][lane * 8 + 4] = make_float4(a[4]*inv, a[5]*inv, a[6]*inv, a[7]*inv);
    }

    // Linear + GELU (wave-local; compiler inserts lgkmcnt waits)
    float r = bld;
    #pragma unroll
    for (int q = 0; q < DIM; q += 4) {
        float4 mv = *(const float4*)&msl[sub][q];
        float4 wv = *(const float4*)&Ws[d][q];
        r = fmaf(mv.x, wv.x, r);
        r = fmaf(mv.y, wv.y, r);
        r = fmaf(mv.z, wv.z, r);
        r = fmaf(mv.w, wv.w, r);
    }
    out[(size_t)node * DIM + d] = 0.5f * r * (1.0f + erff(r * 0.70710678118654752f));
}

// ---------------------------------------------------------------------------
extern "C" void kernel_launch(void* const* d_in, const int* in_sizes, int n_in,
                              void* d_out, int out_size, void* d_ws, size_t ws_size,
                              hipStream_t stream) {
    const float* x    = (const float*)d_in[0];
    const float* curv = (const float*)d_in[1];
    const float* Wc   = (const float*)d_in[2];
    const float* bc   = (const float*)d_in[3];
    const float* Wl   = (const float*)d_in[4];
    const float* bl   = (const float*)d_in[5];
    const int*   edge = (const int*)d_in[6];

    float* out = (float*)d_out;

    // Workspace layout (~32.6 MB)
    int*    cntp = (int*)d_ws;                        // N * 16 (padded, 6.4 MB)
    int*    off  = cntp + (size_t)N_NODES * CPAD;     // N + 1
    int*    bsum = off + N_NODES + 1;                 // 128
    int*    rank = bsum + 128;                        // E (6.4 MB)
    int*    scol = rank + N_EDGES;                    // E (6.4 MB)
    ushort* xh   = (ushort*)(scol + N_EDGES);         // N*64 fp16 (12.8 MB)

    hipMemsetAsync(cntp, 0, (size_t)N_NODES * CPAD * sizeof(int), stream);

    const int cblk = (N_NODES * DIM / 8 + 255) / 256; // 3125
    convert_kernel<<<cblk, 256, 0, stream>>>(x, xh);

    const int qblk = (N_EDGES / 4 + 255) / 256;       // 1563
    rank_kernel<<<qblk, 256, 0, stream>>>(edge, cntp, rank);
    scan_reduce_kernel<<<SCAN_NBLK, SCAN_BS, 0, stream>>>(cntp, bsum);
    scan_top_kernel<<<1, 128, 0, stream>>>(bsum);
    scan_down_kernel<<<SCAN_NBLK, SCAN_BS, 0, stream>>>(cntp, bsum, off);
    scatter_kernel<<<qblk, 256, 0, stream>>>(edge, rank, off, scol);
    node_kernel<<<N_NODES / 4, 256, 0, stream>>>(
        xh, curv, off, scol, Wc, bc, Wl, bl, out);
}

// Round 8
// 226.536 us; speedup vs baseline: 1.0377x; 1.0377x over previous
//
#include <hip/hip_runtime.h>
#include <math.h>

#define N_NODES 100000
#define N_EDGES 1600000
#define DIM 64
#define CPAD 16      // counters padded to one per 64B cache line

#define NPW 8                    // nodes per wave
#define WPB 4                    // waves per block
#define NPB (NPW * WPB)          // 32 nodes per block
#define NODE_BLOCKS (N_NODES / NPB)   // 3125 exact

#define SCAN_BS   256
#define SCAN_EPB  1024
#define SCAN_NBLK ((N_NODES + SCAN_EPB - 1) / SCAN_EPB)   // 98

// sigmoid(s*w+b) = rcp(1 + exp2(s*(-w*log2e) + (-b*log2e)))
__device__ __forceinline__ float fast_gate(float s, float wl, float bl2) {
    return __builtin_amdgcn_rcpf(1.0f + __builtin_amdgcn_exp2f(fmaf(s, wl, bl2)));
}

// ---------------------------------------------------------------------------
// 1) Fused histogram + rank (4 edges/thread, int4 I/O).
// ---------------------------------------------------------------------------
__global__ __launch_bounds__(256) void rank_kernel(
    const int* __restrict__ edge, int* __restrict__ cntp,
    int* __restrict__ rank)
{
    int t = blockIdx.x * 256 + threadIdx.x;
    if (t >= N_EDGES / 4) return;
    int4 r4 = ((const int4*)edge)[t];
    int4 o;
    o.x = atomicAdd(&cntp[(size_t)r4.x * CPAD], 1);
    o.y = atomicAdd(&cntp[(size_t)r4.y * CPAD], 1);
    o.z = atomicAdd(&cntp[(size_t)r4.z * CPAD], 1);
    o.w = atomicAdd(&cntp[(size_t)r4.w * CPAD], 1);
    ((int4*)rank)[t] = o;
}

// ---------------------------------------------------------------------------
// 2a) Per-block reduce of padded cnt.
// ---------------------------------------------------------------------------
__global__ __launch_bounds__(SCAN_BS) void scan_reduce_kernel(
    const int* __restrict__ cntp, int* __restrict__ bsum)
{
    __shared__ int ls[SCAN_BS];
    int base = blockIdx.x * SCAN_EPB;
    int s = 0;
    #pragma unroll
    for (int i = 0; i < 4; ++i) {
        int idx = base + threadIdx.x + i * SCAN_BS;
        s += (idx < N_NODES) ? cntp[(size_t)idx * CPAD] : 0;
    }
    ls[threadIdx.x] = s;
    __syncthreads();
    for (int o = SCAN_BS / 2; o > 0; o >>= 1) {
        if (threadIdx.x < o) ls[threadIdx.x] += ls[threadIdx.x + o];
        __syncthreads();
    }
    if (threadIdx.x == 0) bsum[blockIdx.x] = ls[0];
}

// ---------------------------------------------------------------------------
// 2b) Exclusive scan of the 98 block sums.
// ---------------------------------------------------------------------------
__global__ __launch_bounds__(128) void scan_top_kernel(int* __restrict__ bsum)
{
    __shared__ int ls[SCAN_NBLK];
    if (threadIdx.x < SCAN_NBLK) ls[threadIdx.x] = bsum[threadIdx.x];
    __syncthreads();
    if (threadIdx.x == 0) {
        int run = 0;
        for (int i = 0; i < SCAN_NBLK; ++i) { int t = ls[i]; ls[i] = run; run += t; }
    }
    __syncthreads();
    if (threadIdx.x < SCAN_NBLK) bsum[threadIdx.x] = ls[threadIdx.x];
}

// ---------------------------------------------------------------------------
// 2c) Per-block rescan -> off[] (exclusive prefix; off[N] = E).
// ---------------------------------------------------------------------------
__global__ __launch_bounds__(SCAN_BS) void scan_down_kernel(
    const int* __restrict__ cntp, const int* __restrict__ bsum,
    int* __restrict__ off)
{
    __shared__ int ls[SCAN_BS];
    const int tid  = threadIdx.x;
    const int base = blockIdx.x * SCAN_EPB;

    if (blockIdx.x == 0 && tid == 0) off[N_NODES] = N_EDGES;

    int v[4]; int tsum = 0;
    #pragma unroll
    for (int i = 0; i < 4; ++i) {
        int idx = base + tid * 4 + i;
        v[i] = (idx < N_NODES) ? cntp[(size_t)idx * CPAD] : 0;
        tsum += v[i];
    }
    ls[tid] = tsum;
    __syncthreads();
    for (int o = 1; o < SCAN_BS; o <<= 1) {
        int t = (tid >= o) ? ls[tid - o] : 0;
        __syncthreads();
        ls[tid] += t;
        __syncthreads();
    }
    int run = bsum[blockIdx.x] + ls[tid] - tsum;
    #pragma unroll
    for (int i = 0; i < 4; ++i) {
        int idx = base + tid * 4 + i;
        if (idx < N_NODES) off[idx] = run;
        run += v[i];
    }
}

// ---------------------------------------------------------------------------
// 3) Atomic-free scatter (4 edges/thread): slot = off[row] + rank[e].
//    scol stores are nontemporal: random 4B stores otherwise cost a full
//    64B L2-line writeback each (measured 106MB for a 6.4MB buffer).
// ---------------------------------------------------------------------------
__global__ __launch_bounds__(256) void scatter_kernel(
    const int* __restrict__ edge, const int* __restrict__ rank,
    const int* __restrict__ off,  int* __restrict__ scol)
{
    int t = blockIdx.x * 256 + threadIdx.x;
    if (t >= N_EDGES / 4) return;
    int4 r4 = ((const int4*)edge)[t];
    int4 c4 = ((const int4*)(edge + N_EDGES))[t];
    int4 k4 = ((const int4*)rank)[t];
    __builtin_nontemporal_store(c4.x, &scol[off[r4.x] + k4.x]);
    __builtin_nontemporal_store(c4.y, &scol[off[r4.y] + k4.y]);
    __builtin_nontemporal_store(c4.z, &scol[off[r4.z] + k4.z]);
    __builtin_nontemporal_store(c4.w, &scol[off[r4.w] + k4.w]);
}

// ---------------------------------------------------------------------------
// 4) Per-node fused gather+gate+mean+Linear+GELU (fp32, proven R5 config).
//    32 nodes/block, 8 nodes/wave. Per node:
//      Phase A: lane=edge -> {col, |curv diff|} into LDS (once per edge).
//      Phase B: lane (eg,fg) -> float4 x-gather (32-bit saddr) + 4 gates+fmas.
//      Reduce via shfl_xor(16|32); Linear via float4 LDS reads.
// ---------------------------------------------------------------------------
__global__ __launch_bounds__(256) void node_kernel(
    const float* __restrict__ x,    const float* __restrict__ curv,
    const int*   __restrict__ off,  const int* __restrict__ scol,
    const float* __restrict__ Wc,   const float* __restrict__ bc,
    const float* __restrict__ Wl,   const float* __restrict__ bl,
    float* __restrict__ out)
{
    __shared__ float Ws[64][65];
    __shared__ float msl[WPB][64];
    __shared__ int2  ecd[WPB][64];

    const int tid = threadIdx.x;
    #pragma unroll
    for (int i = tid; i < DIM * DIM; i += 256)
        Ws[i >> 6][i & 63] = Wl[i];
    __syncthreads();

    const int sub  = tid >> 6;          // wave in block
    const int lane = tid & 63;
    const int eg   = lane >> 4;         // edge group 0..3
    const int fg   = (lane & 15) << 2;  // feature quad base
    const int d    = lane;              // output feature for Linear

    const float L2E = 1.44269504088896340736f;
    const float4 wc4 = *(const float4*)&Wc[fg];
    const float4 bc4 = *(const float4*)&bc[fg];
    const float wl0 = -wc4.x * L2E, wl1 = -wc4.y * L2E,
                wl2 = -wc4.z * L2E, wl3 = -wc4.w * L2E;
    const float bq0 = -bc4.x * L2E, bq1 = -bc4.y * L2E,
                bq2 = -bc4.z * L2E, bq3 = -bc4.w * L2E;
    const float bld = bl[d];

    const int nbase = blockIdx.x * NPB + sub * NPW;

    for (int i = 0; i < NPW; ++i) {
        const int   node  = nbase + i;
        const int   start = off[node];
        const int   deg   = off[node + 1] - start;
        const float cn    = curv[node];

        float a0 = 0.f, a1 = 0.f, a2 = 0.f, a3 = 0.f;

        for (int kb = 0; kb < deg; kb += 64) {
            const int pn = min(64, deg - kb);
            // Phase A: one lane per edge
            if (lane < pn) {
                int   c  = scol[start + kb + lane];
                float cd = fabsf(cn - curv[c]);
                ecd[sub][lane] = make_int2(c, __float_as_int(cd));
            }
            // Phase B: group eg handles edges k = eg, eg+4, ... < pn
            int k = eg;
            for (; k + 4 < pn; k += 8) {
                int2 p0 = ecd[sub][k];
                int2 p1 = ecd[sub][k + 4];
                float s0 = __int_as_float(p0.y);
                float s1 = __int_as_float(p1.y);
                float4 x0 = *(const float4*)&x[((unsigned)p0.x << 6) + fg];
                float4 x1 = *(const float4*)&x[((unsigned)p1.x << 6) + fg];
                a0 = fmaf(x0.x, fast_gate(s0, wl0, bq0), a0);
                a1 = fmaf(x0.y, fast_gate(s0, wl1, bq1), a1);
                a2 = fmaf(x0.z, fast_gate(s0, wl2, bq2), a2);
                a3 = fmaf(x0.w, fast_gate(s0, wl3, bq3), a3);
                a0 = fmaf(x1.x, fast_gate(s1, wl0, bq0), a0);
                a1 = fmaf(x1.y, fast_gate(s1, wl1, bq1), a1);
                a2 = fmaf(x1.z, fast_gate(s1, wl2, bq2), a2);
                a3 = fmaf(x1.w, fast_gate(s1, wl3, bq3), a3);
            }
            if (k < pn) {
                int2 p0 = ecd[sub][k];
                float s0 = __int_as_float(p0.y);
                float4 x0 = *(const float4*)&x[((unsigned)p0.x << 6) + fg];
                a0 = fmaf(x0.x, fast_gate(s0, wl0, bq0), a0);
                a1 = fmaf(x0.y, fast_gate(s0, wl1, bq1), a1);
                a2 = fmaf(x0.z, fast_gate(s0, wl2, bq2), a2);
                a3 = fmaf(x0.w, fast_gate(s0, wl3, bq3), a3);
            }
        }

        // sum the 4 edge groups
        a0 += __shfl_xor(a0, 16); a0 += __shfl_xor(a0, 32);
        a1 += __shfl_xor(a1, 16); a1 += __shfl_xor(a1, 32);
        a2 += __shfl_xor(a2, 16); a2 += __shfl_xor(a2, 32);
        a3 += __shfl_xor(a3, 16); a3 += __shfl_xor(a3, 32);

        const float inv = __builtin_amdgcn_rcpf(fmaxf((float)deg, 1.0f));
        if (eg == 0)
            *(float4*)&msl[sub][fg] = make_float4(a0 * inv, a1 * inv, a2 * inv, a3 * inv);

        // Linear + GELU (wave-local; compiler inserts lgkmcnt waits)
        float r = bld;
        #pragma unroll
        for (int q = 0; q < DIM; q += 4) {
            float4 mv = *(const float4*)&msl[sub][q];
            float4 wv = *(const float4*)&Ws[d][q];
            r = fmaf(mv.x, wv.x, r);
            r = fmaf(mv.y, wv.y, r);
            r = fmaf(mv.z, wv.z, r);
            r = fmaf(mv.w, wv.w, r);
        }
        out[(size_t)node * DIM + d] = 0.5f * r * (1.0f + erff(r * 0.70710678118654752f));
    }
}

// ---------------------------------------------------------------------------
extern "C" void kernel_launch(void* const* d_in, const int* in_sizes, int n_in,
                              void* d_out, int out_size, void* d_ws, size_t ws_size,
                              hipStream_t stream) {
    const float* x    = (const float*)d_in[0];
    const float* curv = (const float*)d_in[1];
    const float* Wc   = (const float*)d_in[2];
    const float* bc   = (const float*)d_in[3];
    const float* Wl   = (const float*)d_in[4];
    const float* bl   = (const float*)d_in[5];
    const int*   edge = (const int*)d_in[6];

    float* out = (float*)d_out;

    // Workspace layout (~19.7 MB)
    int* cntp = (int*)d_ws;                          // N * 16 (padded, 6.4 MB)
    int* off  = cntp + (size_t)N_NODES * CPAD;       // N + 1
    int* bsum = off + N_NODES + 1;                   // 128
    int* rank = bsum + 128;                          // E (6.4 MB)
    int* scol = rank + N_EDGES;                      // E (6.4 MB)

    hipMemsetAsync(cntp, 0, (size_t)N_NODES * CPAD * sizeof(int), stream);

    const int qblk = (N_EDGES / 4 + 255) / 256;      // 1563
    rank_kernel<<<qblk, 256, 0, stream>>>(edge, cntp, rank);
    scan_reduce_kernel<<<SCAN_NBLK, SCAN_BS, 0, stream>>>(cntp, bsum);
    scan_top_kernel<<<1, 128, 0, stream>>>(bsum);
    scan_down_kernel<<<SCAN_NBLK, SCAN_BS, 0, stream>>>(cntp, bsum, off);
    scatter_kernel<<<qblk, 256, 0, stream>>>(edge, rank, off, scol);
    node_kernel<<<NODE_BLOCKS, 256, 0, stream>>>(
        x, curv, off, scol, Wc, bc, Wl, bl, out);
}